// Round 2
// baseline (1056.597 us; speedup 1.0000x reference)
//
#include <hip/hip_runtime.h>

// ---------- helpers ----------
typedef __attribute__((ext_vector_type(4))) float f4;
typedef __attribute__((ext_vector_type(8))) short s8;

__device__ inline float b2f(unsigned int u) {
    unsigned int v = u << 16;
    float f;
    __builtin_memcpy(&f, &v, 4);
    return f;
}
__device__ inline unsigned short f2b(float f) {
    unsigned int u;
    __builtin_memcpy(&u, &f, 4);
    unsigned int r = u + 0x7fffu + ((u >> 16) & 1u);
    return (unsigned short)(r >> 16);
}
__device__ inline void async16(const void* g, void* l) {
    __builtin_amdgcn_global_load_lds(
        (const __attribute__((address_space(1))) unsigned int*)g,
        (__attribute__((address_space(3))) unsigned int*)l, 16, 0, 0);
}

#define B_ROWS 8192
#define DIN 1024
#define DH 2048
#define DOUT 1024
#define NE 8
#define NCAT 16384   // NE * DH

// ---------- dtype detection: flag=1 if inputs are fp32, 0 if bf16 ----------
__global__ __launch_bounds__(64) void detect_dtype(const unsigned short* __restrict__ p, int* __restrict__ flag)
{
    const int lane = threadIdx.x;
    int sane = 0;
    for (int i = lane; i < 4096; i += 64) {
        const float a = fabsf(b2f(p[i]));
        if (a > 1e-30f && a < 1e3f) sane++;
    }
    for (int off = 32; off; off >>= 1) sane += __shfl_xor(sane, off, 64);
    if (lane == 0) *flag = (sane < 3600) ? 1 : 0;
}

// ---------- normalize any input tensor to bf16 ----------
__global__ __launch_bounds__(256) void normalize_kernel(const void* __restrict__ src,
                                                        unsigned short* __restrict__ dst,
                                                        const int* __restrict__ flag, int n)
{
    const int i = blockIdx.x * 256 + threadIdx.x;
    if (i >= n) return;
    if (*flag) dst[i] = f2b(((const float*)src)[i]);
    else       dst[i] = ((const unsigned short*)src)[i];
}

// ---------- gating ----------
__global__ __launch_bounds__(256) void gating_kernel(
    const unsigned short* __restrict__ x, const unsigned short* __restrict__ gum,
    const unsigned short* __restrict__ gw, const unsigned short* __restrict__ gb,
    float* __restrict__ probs, float* __restrict__ partials)
{
    const int t = threadIdx.x, wave = t >> 6, lane = t & 63;
    float sp = 0.f, sr = 0.f;
    const int base = blockIdx.x * 32 + wave * 8;
    for (int rr = 0; rr < 8; rr++) {
        const int b = base + rr;
        float acc[8];
#pragma unroll
        for (int e = 0; e < 8; e++) acc[e] = 0.f;
        for (int kk = 0; kk < 16; kk++) {
            const int k = kk * 64 + lane;
            const float xv = b2f(x[(size_t)b * DIN + k]);
            const uint4 wv = *(const uint4*)(gw + (size_t)k * 8);
            acc[0] += xv * b2f(wv.x & 0xffffu); acc[1] += xv * b2f(wv.x >> 16);
            acc[2] += xv * b2f(wv.y & 0xffffu); acc[3] += xv * b2f(wv.y >> 16);
            acc[4] += xv * b2f(wv.z & 0xffffu); acc[5] += xv * b2f(wv.z >> 16);
            acc[6] += xv * b2f(wv.w & 0xffffu); acc[7] += xv * b2f(wv.w >> 16);
        }
#pragma unroll
        for (int e = 0; e < 8; e++)
            for (int off = 32; off; off >>= 1) acc[e] += __shfl_xor(acc[e], off, 64);
        float lg[8], p1[8], p2[8];
        float m1 = -1e30f, m2 = -1e30f;
#pragma unroll
        for (int e = 0; e < 8; e++) {
            lg[e] = acc[e] + b2f(gb[e]);
            p1[e] = (lg[e] + b2f(gum[(size_t)b * 8 + e])) * 1.25f;  // 1/tau
            p2[e] = lg[e] * 1.25f;
            m1 = fmaxf(m1, p1[e]); m2 = fmaxf(m2, p2[e]);
        }
        float s1 = 0.f, s2 = 0.f;
#pragma unroll
        for (int e = 0; e < 8; e++) {
            p1[e] = expf(p1[e] - m1); s1 += p1[e];
            p2[e] = expf(p2[e] - m2); s2 += p2[e];
        }
        const float i1 = 1.f / s1, i2 = 1.f / s2;
        if (lane < 8) {
            const float pv = p1[lane] * i1;
            probs[(size_t)b * 8 + lane] = pv;
            sp += pv;
            sr += p2[lane] * i2;
        }
    }
    __shared__ float red[4][16];
    if (lane < 8) { red[wave][lane] = sp; red[wave][8 + lane] = sr; }
    __syncthreads();
    if (t < 16)
        partials[blockIdx.x * 16 + t] = red[0][t] + red[1][t] + red[2][t] + red[3][t];
}

// ---------- aux loss finalize (dtype-branched output) ----------
__global__ void aux_finalize(const float* __restrict__ partials, void* __restrict__ outp,
                             const int* __restrict__ flag)
{
    __shared__ float fin[16];
    const int t = threadIdx.x;
    if (t < 16) {
        float s = 0.f;
        for (int i = 0; i < 256; i++) s += partials[i * 16 + t];
        fin[t] = s;
    }
    __syncthreads();
    if (t == 0) {
        float ld[8], im[8];
        for (int e = 0; e < 8; e++) { ld[e] = fin[e] / 8192.f; im[e] = fin[8 + e] / 8192.f; }
        float mi = 0.f, ml = 0.f;
        for (int e = 0; e < 8; e++) { mi += im[e]; ml += ld[e]; }
        mi *= 0.125f; ml *= 0.125f;
        float vi = 0.f, vl = 0.f, sw = 0.f;
        for (int e = 0; e < 8; e++) {
            vi += (im[e] - mi) * (im[e] - mi);
            vl += (ld[e] - ml) * (ld[e] - ml);
            sw += im[e] * ld[e];
        }
        const float cvi = sqrtf(vi / 7.f) / (mi + 1e-8f);
        const float cvl = sqrtf(vl / 7.f) / (ml + 1e-8f);
        const float aux = (8.f * sw + cvi + cvl) * 0.05f;
        if (*flag) ((float*)outp)[8388608] = aux;
        else       ((unsigned short*)outp)[8388608] = f2b(aux);
    }
}

// ---------- batched transpose+cvt: per z: src[z][R][C] -> out[z-block][C][R] ----------
__global__ __launch_bounds__(256) void transpose_cvt(
    const void* __restrict__ src, unsigned short* __restrict__ out,
    int R, int C, int ldOut, size_t outEStride, const int* __restrict__ flag)
{
    __shared__ unsigned short tile[64][65];
    const int e = blockIdx.z;
    const size_t eoff = (size_t)e * R * C;
    unsigned short* op = out + (size_t)e * outEStride;
    const int fl = *flag;
    const int tx = threadIdx.x, ty = threadIdx.y;
    const int r0 = blockIdx.y * 64, c0 = blockIdx.x * 64;
    if (fl) {
        const float* in = (const float*)src + eoff;
#pragma unroll
        for (int i = 0; i < 16; i++) {
            const int r = ty + i * 4;
            tile[r][tx] = f2b(in[(size_t)(r0 + r) * C + c0 + tx]);
        }
    } else {
        const unsigned short* in = (const unsigned short*)src + eoff;
#pragma unroll
        for (int i = 0; i < 16; i++) {
            const int r = ty + i * 4;
            tile[r][tx] = in[(size_t)(r0 + r) * C + c0 + tx];
        }
    }
    __syncthreads();
#pragma unroll
    for (int i = 0; i < 16; i++) {
        const int c = ty + i * 4;
        op[(size_t)(c0 + c) * ldOut + r0 + tx] = tile[tx][c];
    }
}

// =====================================================================
// 256x256-tile, BK=64, 8-wave (2Mx4N) deep-pipelined GEMM.
//   LDS: 2 buffers x (A 32KB + B 32KB) = 128KB.
//   Per wave per K-tile: 8 global_load_lds (4 A + 4 B, 1KB each).
//   Swizzle: 16B-granule column s stored at physical (s ^ (row&7));
//     applied on GLOBAL source (linear LDS writes) and ds_read offsets.
//     Per ds_read_b128 the 64 granules spread uniformly over 8 slots ->
//     bank-conflict floor.
//   Sync per K-tile t:
//     vmcnt(8)  : own stage(t) landed (stage(t+1)'s 8 still in flight)
//     barrier   : all waves' stage(t) landed (each checked its own)
//     ds_read tile t + MFMA (compiler lgkm waits; all reads consumed)
//     lgkm(0)+sched_barrier+barrier : all waves done READING buf[t&1]
//     stage(t+2) -> buf[t&1]        : issued only after that barrier => safe
// =====================================================================
#define MFMA16(a, b, c) __builtin_amdgcn_mfma_f32_16x16x32_bf16(a, b, c, 0, 0, 0)

template<int K, int EPI>
__global__ __launch_bounds__(512, 2) void gemm256(
    const unsigned short* __restrict__ A,
    const unsigned short* __restrict__ Bt,
    const unsigned short* __restrict__ bias,   // EPI0
    const float* __restrict__ probs,           // EPI0
    unsigned short* __restrict__ outH,         // EPI0
    float* __restrict__ partial,               // EPI1
    int rows, int klen, int SWZ)
{
    __shared__ __align__(16) char smem[131072];
    const int t = threadIdx.x;
    const int w = t >> 6, l = t & 63;
    const int l15 = l & 15, q = l >> 4;
    const int wm = w >> 2, wn = w & 3;

    int bx = blockIdx.x, by = blockIdx.y;
    if (SWZ) {  // XCD-aware bijective remap (grid.x*grid.y % 8 == 0 guaranteed by launch)
        const int n = gridDim.x * gridDim.y;
        int bid = by * gridDim.x + bx;
        const int c = n >> 3;
        bid = (bid & 7) * c + (bid >> 3);
        bx = bid % gridDim.x; by = bid / gridDim.x;
    }
    const int m0 = bx * 256, n0 = by * 256;
    const int kstart = blockIdx.z * klen;
    const int NT = klen >> 6;

    // staging source pointers: instruction i covers tile rows [(w*4+i)*8, +8)
    const int srow = l >> 3;                 // 0..7 within the 8-row slab
    const int swz = (l & 7) ^ srow;          // swizzled granule column in source
    const char* pa[4]; const char* pb[4];
#pragma unroll
    for (int i = 0; i < 4; i++) {
        const int ra = m0 + (w * 4 + i) * 8 + srow;
        const int rb = n0 + (w * 4 + i) * 8 + srow;
        pa[i] = (const char*)(A  + (size_t)ra * K + kstart + swz * 8);
        pb[i] = (const char*)(Bt + (size_t)rb * K + kstart + swz * 8);
    }

    auto stage = [&](int kt, int bsel) {
        char* Ab = smem + bsel * 65536;
        char* Bb = Ab + 32768;
        const size_t kb = (size_t)kt * 128;
#pragma unroll
        for (int i = 0; i < 4; i++) async16(pa[i] + kb, Ab + (w * 4 + i) * 1024);
#pragma unroll
        for (int i = 0; i < 4; i++) async16(pb[i] + kb, Bb + (w * 4 + i) * 1024);
    };

    f4 acc[8][4];
#pragma unroll
    for (int i = 0; i < 8; i++)
#pragma unroll
        for (int j = 0; j < 4; j++) { acc[i][j][0] = 0.f; acc[i][j][1] = 0.f; acc[i][j][2] = 0.f; acc[i][j][3] = 0.f; }

    // fragment read offsets: row&7 == l&7 for all frag rows (mf*16, wm*128, wn*64 are mult of 8)
    const int arow0 = (wm * 128 + l15) * 128;
    const int brow0 = (wn * 64 + l15) * 128;
    int sz[2];
#pragma unroll
    for (int kh = 0; kh < 2; kh++) sz[kh] = (((kh * 4 + q) ^ (l & 7)) << 4);

    stage(0, 0);
    stage(1, 1);

    for (int kt = 0; kt < NT; ++kt) {
        if (kt + 1 < NT) asm volatile("s_waitcnt vmcnt(8)" ::: "memory");
        else             asm volatile("s_waitcnt vmcnt(0)" ::: "memory");
        __builtin_amdgcn_s_barrier();
        const char* Ab = smem + (kt & 1) * 65536;
        const char* Bb = Ab + 32768;
        s8 Af[4][2], Bf[4][2];
#pragma unroll
        for (int mf = 0; mf < 4; mf++)
#pragma unroll
            for (int kh = 0; kh < 2; kh++)
                Af[mf][kh] = *(const s8*)(Ab + arow0 + mf * 2048 + sz[kh]);
#pragma unroll
        for (int nf = 0; nf < 4; nf++)
#pragma unroll
            for (int kh = 0; kh < 2; kh++)
                Bf[nf][kh] = *(const s8*)(Bb + brow0 + nf * 2048 + sz[kh]);
        __builtin_amdgcn_s_setprio(1);
#pragma unroll
        for (int mf = 0; mf < 4; mf++)
#pragma unroll
            for (int nf = 0; nf < 4; nf++) {
                acc[mf][nf] = MFMA16(Af[mf][0], Bf[nf][0], acc[mf][nf]);
                acc[mf][nf] = MFMA16(Af[mf][1], Bf[nf][1], acc[mf][nf]);
            }
        __builtin_amdgcn_s_setprio(0);
#pragma unroll
        for (int mf = 0; mf < 4; mf++)
#pragma unroll
            for (int kh = 0; kh < 2; kh++)
                Af[mf][kh] = *(const s8*)(Ab + arow0 + (mf + 4) * 2048 + sz[kh]);
        __builtin_amdgcn_s_setprio(1);
#pragma unroll
        for (int mf = 0; mf < 4; mf++)
#pragma unroll
            for (int nf = 0; nf < 4; nf++) {
                acc[mf + 4][nf] = MFMA16(Af[mf][0], Bf[nf][0], acc[mf + 4][nf]);
                acc[mf + 4][nf] = MFMA16(Af[mf][1], Bf[nf][1], acc[mf + 4][nf]);
            }
        __builtin_amdgcn_s_setprio(0);
        asm volatile("s_waitcnt lgkmcnt(0)" ::: "memory");
        __builtin_amdgcn_sched_barrier(0);
        __builtin_amdgcn_s_barrier();
        if (kt + 2 < NT) stage(kt + 2, kt & 1);
    }

    if (EPI == 0) {
        // relu(acc + b1cat[gn]) * probs[gm][e] -> bf16 Hcat
#pragma unroll
        for (int nf = 0; nf < 4; nf++) {
            const int gn = n0 + wn * 64 + nf * 16 + l15;
            const int e = gn >> 11;
            const float bval = b2f(bias[gn]);
#pragma unroll
            for (int mf = 0; mf < 8; mf++) {
                const int gmB = m0 + wm * 128 + mf * 16 + q * 4;
#pragma unroll
                for (int r = 0; r < 4; r++) {
                    const int gm = gmB + r;
                    const float pv = probs[(size_t)gm * 8 + e];
                    const float v = fmaxf(acc[mf][nf][r] + bval, 0.f) * pv;
                    outH[(size_t)gm * NCAT + gn] = f2b(v);
                }
            }
        }
    } else {
        float* pp = partial + (size_t)blockIdx.z * rows * DOUT;
#pragma unroll
        for (int mf = 0; mf < 8; mf++) {
            const int gmB = m0 + wm * 128 + mf * 16 + q * 4;
#pragma unroll
            for (int nf = 0; nf < 4; nf++) {
                const int gn = n0 + wn * 64 + nf * 16 + l15;
#pragma unroll
                for (int r = 0; r < 4; r++)
                    pp[(size_t)(gmB + r) * DOUT + gn] = acc[mf][nf][r];
            }
        }
    }
}

// ---------- out finalize: sum split-K partials + probs.b2 bias, dtype-branched write ----------
__global__ __launch_bounds__(256) void out_finalize(
    const float* __restrict__ partial, const unsigned short* __restrict__ b2,
    const float* __restrict__ probs, void* __restrict__ outp, size_t outOff,
    const int* __restrict__ flag, int rows, int nks)
{
    const int idx = blockIdx.x * 256 + threadIdx.x;
    if (idx >= rows * DOUT) return;
    const int m = idx >> 10, n = idx & (DOUT - 1);
    float v = 0.f;
    for (int ks = 0; ks < nks; ks++)
        v += partial[(size_t)ks * rows * DOUT + idx];
    const f4 p0 = *(const f4*)(probs + (size_t)m * 8);
    const f4 p1 = *(const f4*)(probs + (size_t)m * 8 + 4);
    v += p0[0] * b2f(b2[n])            + p0[1] * b2f(b2[DOUT + n])
       + p0[2] * b2f(b2[2 * DOUT + n]) + p0[3] * b2f(b2[3 * DOUT + n])
       + p1[0] * b2f(b2[4 * DOUT + n]) + p1[1] * b2f(b2[5 * DOUT + n])
       + p1[2] * b2f(b2[6 * DOUT + n]) + p1[3] * b2f(b2[7 * DOUT + n]);
    const size_t oi = outOff + ((size_t)m * DOUT) + n;
    if (*flag) ((float*)outp)[oi] = v;
    else       ((unsigned short*)outp)[oi] = f2b(v);
}

extern "C" void kernel_launch(void* const* d_in, const int* in_sizes, int n_in,
                              void* d_out, int out_size, void* d_ws, size_t ws_size,
                              hipStream_t stream)
{
    const void* x   = d_in[0];
    const void* gum = d_in[1];
    const void* gw  = d_in[2];
    const void* gb  = d_in[3];
    const void* w1  = d_in[4];
    const void* b1  = d_in[5];
    const void* w2  = d_in[6];
    const void* b2  = d_in[7];

    char* ws = (char*)d_ws;
    size_t cur = 0;
    auto alloc = [&](size_t bytes) { size_t p = cur; cur = (cur + bytes + 255) & ~(size_t)255; return p; };

    int* flag              = (int*)(ws + alloc(256));
    float* probs           = (float*)(ws + alloc(8192 * 8 * 4));
    float* partials        = (float*)(ws + alloc(256 * 16 * 4));
    unsigned short* xn     = (unsigned short*)(ws + alloc((size_t)B_ROWS * DIN * 2));
    unsigned short* gumn   = (unsigned short*)(ws + alloc((size_t)B_ROWS * 8 * 2));
    unsigned short* gwn    = (unsigned short*)(ws + alloc((size_t)DIN * 8 * 2));
    unsigned short* gbn    = (unsigned short*)(ws + alloc(8 * 2));
    unsigned short* b1n    = (unsigned short*)(ws + alloc((size_t)NE * DH * 2));
    unsigned short* b2n    = (unsigned short*)(ws + alloc((size_t)NE * DOUT * 2));
    unsigned short* w1Tcat = (unsigned short*)(ws + alloc((size_t)NCAT * DIN * 2));   // 32 MiB
    unsigned short* w2Tcat = (unsigned short*)(ws + alloc((size_t)DOUT * NCAT * 2));  // 32 MiB
    const size_t fixed = cur;  // ~81 MB

    // Chunk sizing. Invariant: KS*R == 16384 so gemm_out grid = (R/256)*4*KS == 256
    // blocks exactly, and the split-K partial buffer is a constant 64 MB.
    int R = B_ROWS, KS;
    for (;;) {
        KS = 16384 / R;
        const size_t need = fixed + (size_t)R * (NCAT * 2) + (size_t)KS * R * DOUT * 4;
        if (R <= 512 || need <= ws_size) break;
        R >>= 1;
    }
    const int klen = 16384 / KS;   // multiple of 64; NT = klen/64 >= 2
    unsigned short* Hcat = (unsigned short*)(ws + fixed);
    float* partial = (float*)(ws + fixed + (size_t)R * (NCAT * 2));

    detect_dtype<<<1, 64, 0, stream>>>((const unsigned short*)x, flag);

    normalize_kernel<<<(B_ROWS * DIN + 255) / 256, 256, 0, stream>>>(x, xn, flag, B_ROWS * DIN);
    normalize_kernel<<<(B_ROWS * 8 + 255) / 256, 256, 0, stream>>>(gum, gumn, flag, B_ROWS * 8);
    normalize_kernel<<<(DIN * 8 + 255) / 256, 256, 0, stream>>>(gw, gwn, flag, DIN * 8);
    normalize_kernel<<<1, 256, 0, stream>>>(gb, gbn, flag, 8);
    normalize_kernel<<<(NE * DH + 255) / 256, 256, 0, stream>>>(b1, b1n, flag, NE * DH);
    normalize_kernel<<<(NE * DOUT + 255) / 256, 256, 0, stream>>>(b2, b2n, flag, NE * DOUT);

    gating_kernel<<<256, 256, 0, stream>>>(xn, gumn, gwn, gbn, probs, partials);
    aux_finalize<<<1, 64, 0, stream>>>(partials, d_out, flag);

    transpose_cvt<<<dim3(DH / 64, DIN / 64, NE), dim3(64, 4), 0, stream>>>(
        w1, w1Tcat, DIN, DH, DIN, (size_t)DH * DIN, flag);
    transpose_cvt<<<dim3(DOUT / 64, DH / 64, NE), dim3(64, 4), 0, stream>>>(
        w2, w2Tcat, DH, DOUT, NCAT, (size_t)DH, flag);

    for (int c0 = 0; c0 < B_ROWS; c0 += R) {
        gemm256<DIN, 0><<<dim3(R / 256, NCAT / 256, 1), 512, 0, stream>>>(
            xn + (size_t)c0 * DIN, w1Tcat, b1n, probs + (size_t)c0 * 8, Hcat,
            nullptr, R, DIN, 1);
        gemm256<NCAT, 1><<<dim3(R / 256, DOUT / 256, KS), 512, 0, stream>>>(
            Hcat, w2Tcat, nullptr, nullptr, nullptr,
            partial, R, klen, 0);
        out_finalize<<<(R * DOUT) / 256, 256, 0, stream>>>(
            partial, b2n, probs + (size_t)c0 * 8, d_out, (size_t)c0 * DOUT, flag, R, KS);
    }
}

// Round 4
// 1032.596 us; speedup vs baseline: 1.0232x; 1.0232x over previous
//
#include <hip/hip_runtime.h>

// ---------- helpers ----------
typedef __attribute__((ext_vector_type(4))) float f4;
typedef __attribute__((ext_vector_type(8))) short s8;

__device__ inline float b2f(unsigned int u) {
    unsigned int v = u << 16;
    float f;
    __builtin_memcpy(&f, &v, 4);
    return f;
}
__device__ inline unsigned short f2b(float f) {
    unsigned int u;
    __builtin_memcpy(&u, &f, 4);
    unsigned int r = u + 0x7fffu + ((u >> 16) & 1u);
    return (unsigned short)(r >> 16);
}
__device__ inline void async16(const void* g, void* l) {
    __builtin_amdgcn_global_load_lds(
        (const __attribute__((address_space(1))) unsigned int*)g,
        (__attribute__((address_space(3))) unsigned int*)l, 16, 0, 0);
}

#define B_ROWS 8192
#define DIN 1024
#define DH 2048
#define DOUT 1024
#define NE 8
#define NCAT 16384   // NE * DH

// ---------- dtype detection: flag=1 if inputs are fp32, 0 if bf16 ----------
__global__ __launch_bounds__(64) void detect_dtype(const unsigned short* __restrict__ p, int* __restrict__ flag)
{
    const int lane = threadIdx.x;
    int sane = 0;
    for (int i = lane; i < 4096; i += 64) {
        const float a = fabsf(b2f(p[i]));
        if (a > 1e-30f && a < 1e3f) sane++;
    }
    for (int off = 32; off; off >>= 1) sane += __shfl_xor(sane, off, 64);
    if (lane == 0) *flag = (sane < 3600) ? 1 : 0;
}

// ---------- normalize any input tensor to bf16 ----------
__global__ __launch_bounds__(256) void normalize_kernel(const void* __restrict__ src,
                                                        unsigned short* __restrict__ dst,
                                                        const int* __restrict__ flag, int n)
{
    const int i = blockIdx.x * 256 + threadIdx.x;
    if (i >= n) return;
    if (*flag) dst[i] = f2b(((const float*)src)[i]);
    else       dst[i] = ((const unsigned short*)src)[i];
}

// ---------- gating ----------
__global__ __launch_bounds__(256) void gating_kernel(
    const unsigned short* __restrict__ x, const unsigned short* __restrict__ gum,
    const unsigned short* __restrict__ gw, const unsigned short* __restrict__ gb,
    float* __restrict__ probs, float* __restrict__ partials)
{
    const int t = threadIdx.x, wave = t >> 6, lane = t & 63;
    float sp = 0.f, sr = 0.f;
    const int base = blockIdx.x * 32 + wave * 8;
    for (int rr = 0; rr < 8; rr++) {
        const int b = base + rr;
        float acc[8];
#pragma unroll
        for (int e = 0; e < 8; e++) acc[e] = 0.f;
        for (int kk = 0; kk < 16; kk++) {
            const int k = kk * 64 + lane;
            const float xv = b2f(x[(size_t)b * DIN + k]);
            const uint4 wv = *(const uint4*)(gw + (size_t)k * 8);
            acc[0] += xv * b2f(wv.x & 0xffffu); acc[1] += xv * b2f(wv.x >> 16);
            acc[2] += xv * b2f(wv.y & 0xffffu); acc[3] += xv * b2f(wv.y >> 16);
            acc[4] += xv * b2f(wv.z & 0xffffu); acc[5] += xv * b2f(wv.z >> 16);
            acc[6] += xv * b2f(wv.w & 0xffffu); acc[7] += xv * b2f(wv.w >> 16);
        }
#pragma unroll
        for (int e = 0; e < 8; e++)
            for (int off = 32; off; off >>= 1) acc[e] += __shfl_xor(acc[e], off, 64);
        float lg[8], p1[8], p2[8];
        float m1 = -1e30f, m2 = -1e30f;
#pragma unroll
        for (int e = 0; e < 8; e++) {
            lg[e] = acc[e] + b2f(gb[e]);
            p1[e] = (lg[e] + b2f(gum[(size_t)b * 8 + e])) * 1.25f;  // 1/tau
            p2[e] = lg[e] * 1.25f;
            m1 = fmaxf(m1, p1[e]); m2 = fmaxf(m2, p2[e]);
        }
        float s1 = 0.f, s2 = 0.f;
#pragma unroll
        for (int e = 0; e < 8; e++) {
            p1[e] = expf(p1[e] - m1); s1 += p1[e];
            p2[e] = expf(p2[e] - m2); s2 += p2[e];
        }
        const float i1 = 1.f / s1, i2 = 1.f / s2;
        if (lane < 8) {
            const float pv = p1[lane] * i1;
            probs[(size_t)b * 8 + lane] = pv;
            sp += pv;
            sr += p2[lane] * i2;
        }
    }
    __shared__ float red[4][16];
    if (lane < 8) { red[wave][lane] = sp; red[wave][8 + lane] = sr; }
    __syncthreads();
    if (t < 16)
        partials[blockIdx.x * 16 + t] = red[0][t] + red[1][t] + red[2][t] + red[3][t];
}

// ---------- aux loss finalize (dtype-branched output) ----------
__global__ void aux_finalize(const float* __restrict__ partials, void* __restrict__ outp,
                             const int* __restrict__ flag)
{
    __shared__ float fin[16];
    const int t = threadIdx.x;
    if (t < 16) {
        float s = 0.f;
        for (int i = 0; i < 256; i++) s += partials[i * 16 + t];
        fin[t] = s;
    }
    __syncthreads();
    if (t == 0) {
        float ld[8], im[8];
        for (int e = 0; e < 8; e++) { ld[e] = fin[e] / 8192.f; im[e] = fin[8 + e] / 8192.f; }
        float mi = 0.f, ml = 0.f;
        for (int e = 0; e < 8; e++) { mi += im[e]; ml += ld[e]; }
        mi *= 0.125f; ml *= 0.125f;
        float vi = 0.f, vl = 0.f, sw = 0.f;
        for (int e = 0; e < 8; e++) {
            vi += (im[e] - mi) * (im[e] - mi);
            vl += (ld[e] - ml) * (ld[e] - ml);
            sw += im[e] * ld[e];
        }
        const float cvi = sqrtf(vi / 7.f) / (mi + 1e-8f);
        const float cvl = sqrtf(vl / 7.f) / (ml + 1e-8f);
        const float aux = (8.f * sw + cvi + cvl) * 0.05f;
        if (*flag) ((float*)outp)[8388608] = aux;
        else       ((unsigned short*)outp)[8388608] = f2b(aux);
    }
}

// ---------- batched transpose+cvt: per z: src[z][R][C] -> out[z-block][C][R] ----------
__global__ __launch_bounds__(256) void transpose_cvt(
    const void* __restrict__ src, unsigned short* __restrict__ out,
    int R, int C, int ldOut, size_t outEStride, const int* __restrict__ flag)
{
    __shared__ unsigned short tile[64][65];
    const int e = blockIdx.z;
    const size_t eoff = (size_t)e * R * C;
    unsigned short* op = out + (size_t)e * outEStride;
    const int fl = *flag;
    const int tx = threadIdx.x, ty = threadIdx.y;
    const int r0 = blockIdx.y * 64, c0 = blockIdx.x * 64;
    if (fl) {
        const float* in = (const float*)src + eoff;
#pragma unroll
        for (int i = 0; i < 16; i++) {
            const int r = ty + i * 4;
            tile[r][tx] = f2b(in[(size_t)(r0 + r) * C + c0 + tx]);
        }
    } else {
        const unsigned short* in = (const unsigned short*)src + eoff;
#pragma unroll
        for (int i = 0; i < 16; i++) {
            const int r = ty + i * 4;
            tile[r][tx] = in[(size_t)(r0 + r) * C + c0 + tx];
        }
    }
    __syncthreads();
#pragma unroll
    for (int i = 0; i < 16; i++) {
        const int c = ty + i * 4;
        op[(size_t)(c0 + c) * ldOut + r0 + tx] = tile[tx][c];
    }
}

// =====================================================================
// 256x256-tile, BK=64, 8-wave (2Mx4N), 8-phase counted-vmcnt GEMM.
// Flattened (no lambdas/templates in the hot loop) — same schedule as the
// Round-3 design; see vmcnt ledger in comments below.
//
// LDS per buffer: A 32KB + B 32KB; K-HALF-major layout:
//   byte(row, kh, slot) = kh*16384 + row*64 + slot*16.
//   Swizzle: phys slot = logical_q ^ ((row>>1)&3) — applied on GLOBAL src
//   (global_load_lds writes linearly) and on ds_read offsets. Conflict-free.
//
// Phases per K-tile t (d=t&1): ph0=(kh0,nf01) ph1=(kh0,nf23) ph2=(kh1,nf01)
//   ph3=(kh1,nf23), 16 MFMA each; Af[8] loaded at ph0/ph2, held one phase.
// Staging of tile t+1 into buffer d^1: one 16KB half-tile per phase,
//   order AK0,BK0,AK1,BK1 (2 global_load_lds per wave each).
// vmcnt ledger (per wave): at ph1-tail outstanding =
//   {AK1(t),BK1(t),AK0(t+1),BK0(t+1)} = 8 -> vmcnt(4) proves AK1(t),BK1(t)
//   landed; barrier -> ph2's kh1 reads safe. At ph3-tail outstanding =
//   {AK1(t),BK1(t) retired; AK0(t+1),BK0(t+1),AK1(t+1),BK1(t+1)} = 8 ->
//   vmcnt(4) proves AK0(t+1),BK0(t+1) landed -> next ph0 safe.
//   Loads never drain to 0 in the main loop; last tile peeled.
// Buffer-reuse: writes to buffer nd are issued only after the barrier that
//   follows the MFMA consumption (lgkm-complete) of nd's previous data.
// =====================================================================
#define MFMA16(a, b, c) __builtin_amdgcn_mfma_f32_16x16x32_bf16(a, b, c, 0, 0, 0)

#define PHASE(KH, NFH, STAGE_STMT, TAIL_STMT)                                   \
    {                                                                           \
        if ((NFH) == 0) {                                                       \
            _Pragma("unroll")                                                   \
            for (int mf = 0; mf < 8; mf++)                                      \
                Af[mf] = *(const s8*)(Ab + (KH) * 16384 + aoff[mf]);            \
        }                                                                       \
        const s8 Bf0 = *(const s8*)(Bb + (KH) * 16384 + boff[(NFH) * 2 + 0]);   \
        const s8 Bf1 = *(const s8*)(Bb + (KH) * 16384 + boff[(NFH) * 2 + 1]);   \
        STAGE_STMT;                                                             \
        __builtin_amdgcn_s_barrier();                                           \
        __builtin_amdgcn_s_setprio(1);                                          \
        _Pragma("unroll")                                                       \
        for (int mf = 0; mf < 8; mf++) {                                        \
            acc[mf][(NFH) * 2 + 0] = MFMA16(Af[mf], Bf0, acc[mf][(NFH) * 2 + 0]); \
            acc[mf][(NFH) * 2 + 1] = MFMA16(Af[mf], Bf1, acc[mf][(NFH) * 2 + 1]); \
        }                                                                       \
        __builtin_amdgcn_s_setprio(0);                                          \
        TAIL_STMT;                                                              \
        __builtin_amdgcn_s_barrier();                                           \
    }

#define STG_A(nd, kh, ktn)                                                      \
    {                                                                           \
        char* dst_ = smem + (nd) * 65536 + (kh) * 16384 + w2 * 1024;            \
        const size_t kb_ = (size_t)(ktn) * 128 + (kh) * 64;                     \
        async16(paC0 + kb_, dst_);                                              \
        async16(paC1 + kb_, dst_ + 1024);                                       \
    }
#define STG_B(nd, kh, ktn)                                                      \
    {                                                                           \
        char* dst_ = smem + (nd) * 65536 + 32768 + (kh) * 16384 + w2 * 1024;    \
        const size_t kb_ = (size_t)(ktn) * 128 + (kh) * 64;                     \
        async16(pbC0 + kb_, dst_);                                              \
        async16(pbC1 + kb_, dst_ + 1024);                                       \
    }

#define VM4  asm volatile("s_waitcnt vmcnt(4)" ::: "memory")
#define VM0  asm volatile("s_waitcnt vmcnt(0)" ::: "memory")

template<int K, int EPI>
__global__ __launch_bounds__(512, 2) void gemm256(
    const unsigned short* __restrict__ A,
    const unsigned short* __restrict__ Bt,
    const unsigned short* __restrict__ bias,   // EPI0
    const float* __restrict__ probs,           // EPI0
    unsigned short* __restrict__ outH,         // EPI0
    float* __restrict__ partial,               // EPI1
    int rows, int klen, int SWZ)
{
    __shared__ __align__(16) char smem[131072];
    const int t = threadIdx.x;
    const int w = t >> 6, l = t & 63;
    const int l15 = l & 15, q = l >> 4;
    const int wm = w >> 2, wn = w & 3;

    int bx = blockIdx.x, by = blockIdx.y;
    if (SWZ) {  // XCD-aware bijective remap (grid.x*grid.y % 8 == 0)
        const int n = gridDim.x * gridDim.y;
        int bid = by * gridDim.x + bx;
        const int c = n >> 3;
        bid = (bid & 7) * c + (bid >> 3);
        bx = bid % gridDim.x; by = bid / gridDim.x;
    }
    const int m0 = bx * 256, n0 = by * 256;
    const int kstart = blockIdx.z * klen;
    const int NT = klen >> 6;

    // staging source pointers (pre-swizzled global addresses).
    // Wave w stages tile rows [w*32, w*32+32): instr pair covers 16 rows each.
    // lane l -> row (l>>2) within 16-row slab, phys slot l&3,
    // logical granule (l&3)^((l>>3)&3)  [= (row>>1)&3 key].
    const int w2 = w * 2;
    const int srow0 = w2 * 16 + (l >> 2);
    const int srow1 = srow0 + 16;
    const int gr = ((l & 3) ^ ((l >> 3) & 3)) * 8;   // element offset in 32-el half
    const char* paC0 = (const char*)(A  + (size_t)(m0 + srow0) * K + kstart + gr);
    const char* paC1 = (const char*)(A  + (size_t)(m0 + srow1) * K + kstart + gr);
    const char* pbC0 = (const char*)(Bt + (size_t)(n0 + srow0) * K + kstart + gr);
    const char* pbC1 = (const char*)(Bt + (size_t)(n0 + srow1) * K + kstart + gr);

    // fragment read offsets: byte = row*64 + ((q ^ ((row>>1)&3))<<4), row&15==l15
    const int skey = ((q ^ ((l15 >> 1) & 3)) << 4);
    int aoff[8]; int boff[4];
#pragma unroll
    for (int mf = 0; mf < 8; mf++) aoff[mf] = (wm * 128 + mf * 16 + l15) * 64 + skey;
#pragma unroll
    for (int nf = 0; nf < 4; nf++) boff[nf] = (wn * 64 + nf * 16 + l15) * 64 + skey;

    f4 acc[8][4];
#pragma unroll
    for (int i = 0; i < 8; i++)
#pragma unroll
        for (int j = 0; j < 4; j++) { acc[i][j][0] = 0.f; acc[i][j][1] = 0.f; acc[i][j][2] = 0.f; acc[i][j][3] = 0.f; }

    s8 Af[8];

    // prologue: stage tile 0 (AK0,BK0,AK1,BK1); guard kh0 halves only.
    STG_A(0, 0, 0); STG_B(0, 0, 0); STG_A(0, 1, 0); STG_B(0, 1, 0);
    VM4;
    __builtin_amdgcn_s_barrier();

    int kt = 0;
    for (; kt + 1 < NT; ++kt) {
        const int d = kt & 1, nd = d ^ 1;
        const char* Ab = smem + d * 65536;
        const char* Bb = Ab + 32768;
        PHASE(0, 0, STG_A(nd, 0, kt + 1), (void)0)
        PHASE(0, 1, STG_B(nd, 0, kt + 1), VM4)
        PHASE(1, 0, STG_A(nd, 1, kt + 1), (void)0)
        PHASE(1, 1, STG_B(nd, 1, kt + 1), VM4)
    }
    {   // peeled last tile: no staging; drain before kh1 reads
        const int d = kt & 1;
        const char* Ab = smem + d * 65536;
        const char* Bb = Ab + 32768;
        PHASE(0, 0, (void)0, (void)0)
        PHASE(0, 1, (void)0, VM0)
        PHASE(1, 0, (void)0, (void)0)
        PHASE(1, 1, (void)0, (void)0)
    }

    if (EPI == 0) {
        // relu(acc + b1cat[gn]) * probs[gm][e] -> bf16 Hcat
#pragma unroll
        for (int nf = 0; nf < 4; nf++) {
            const int gn = n0 + wn * 64 + nf * 16 + l15;
            const int e = gn >> 11;
            const float bval = b2f(bias[gn]);
#pragma unroll
            for (int mf = 0; mf < 8; mf++) {
                const int gmB = m0 + wm * 128 + mf * 16 + q * 4;
#pragma unroll
                for (int r = 0; r < 4; r++) {
                    const int gm = gmB + r;
                    const float pv = probs[(size_t)gm * 8 + e];
                    const float v = fmaxf(acc[mf][nf][r] + bval, 0.f) * pv;
                    outH[(size_t)gm * NCAT + gn] = f2b(v);
                }
            }
        }
    } else {
        float* pp = partial + (size_t)blockIdx.z * rows * DOUT;
#pragma unroll
        for (int mf = 0; mf < 8; mf++) {
            const int gmB = m0 + wm * 128 + mf * 16 + q * 4;
#pragma unroll
            for (int nf = 0; nf < 4; nf++) {
                const int gn = n0 + wn * 64 + nf * 16 + l15;
#pragma unroll
                for (int r = 0; r < 4; r++)
                    pp[(size_t)(gmB + r) * DOUT + gn] = acc[mf][nf][r];
            }
        }
    }
}

// ---------- out finalize: sum split-K partials + probs.b2 bias, dtype-branched write ----------
__global__ __launch_bounds__(256) void out_finalize(
    const float* __restrict__ partial, const unsigned short* __restrict__ b2,
    const float* __restrict__ probs, void* __restrict__ outp, size_t outOff,
    const int* __restrict__ flag, int rows, int nks)
{
    const int idx = blockIdx.x * 256 + threadIdx.x;
    if (idx >= rows * DOUT) return;
    const int m = idx >> 10, n = idx & (DOUT - 1);
    float v = 0.f;
    for (int ks = 0; ks < nks; ks++)
        v += partial[(size_t)ks * rows * DOUT + idx];
    const f4 p0 = *(const f4*)(probs + (size_t)m * 8);
    const f4 p1 = *(const f4*)(probs + (size_t)m * 8 + 4);
    v += p0[0] * b2f(b2[n])            + p0[1] * b2f(b2[DOUT + n])
       + p0[2] * b2f(b2[2 * DOUT + n]) + p0[3] * b2f(b2[3 * DOUT + n])
       + p1[0] * b2f(b2[4 * DOUT + n]) + p1[1] * b2f(b2[5 * DOUT + n])
       + p1[2] * b2f(b2[6 * DOUT + n]) + p1[3] * b2f(b2[7 * DOUT + n]);
    const size_t oi = outOff + ((size_t)m * DOUT) + n;
    if (*flag) ((float*)outp)[oi] = v;
    else       ((unsigned short*)outp)[oi] = f2b(v);
}

extern "C" void kernel_launch(void* const* d_in, const int* in_sizes, int n_in,
                              void* d_out, int out_size, void* d_ws, size_t ws_size,
                              hipStream_t stream)
{
    const void* x   = d_in[0];
    const void* gum = d_in[1];
    const void* gw  = d_in[2];
    const void* gb  = d_in[3];
    const void* w1  = d_in[4];
    const void* b1  = d_in[5];
    const void* w2  = d_in[6];
    const void* b2  = d_in[7];

    char* ws = (char*)d_ws;
    size_t cur = 0;
    auto alloc = [&](size_t bytes) { size_t p = cur; cur = (cur + bytes + 255) & ~(size_t)255; return p; };

    int* flag              = (int*)(ws + alloc(256));
    float* probs           = (float*)(ws + alloc(8192 * 8 * 4));
    float* partials        = (float*)(ws + alloc(256 * 16 * 4));
    unsigned short* xn     = (unsigned short*)(ws + alloc((size_t)B_ROWS * DIN * 2));
    unsigned short* gumn   = (unsigned short*)(ws + alloc((size_t)B_ROWS * 8 * 2));
    unsigned short* gwn    = (unsigned short*)(ws + alloc((size_t)DIN * 8 * 2));
    unsigned short* gbn    = (unsigned short*)(ws + alloc(8 * 2));
    unsigned short* b1n    = (unsigned short*)(ws + alloc((size_t)NE * DH * 2));
    unsigned short* b2n    = (unsigned short*)(ws + alloc((size_t)NE * DOUT * 2));
    unsigned short* w1Tcat = (unsigned short*)(ws + alloc((size_t)NCAT * DIN * 2));   // 32 MiB
    unsigned short* w2Tcat = (unsigned short*)(ws + alloc((size_t)DOUT * NCAT * 2));  // 32 MiB
    const size_t fixed = cur;  // ~81 MB

    // Chunk sizing. Invariant: KS*R == 16384 -> gemm_out grid = 256 blocks,
    // partial buffer constant 64 MB.
    int R = B_ROWS, KS;
    for (;;) {
        KS = 16384 / R;
        const size_t need = fixed + (size_t)R * (NCAT * 2) + (size_t)KS * R * DOUT * 4;
        if (R <= 512 || need <= ws_size) break;
        R >>= 1;
    }
    const int klen = 16384 / KS;   // multiple of 64; NT = klen/64 >= 2
    unsigned short* Hcat = (unsigned short*)(ws + fixed);
    float* partial = (float*)(ws + fixed + (size_t)R * (NCAT * 2));

    detect_dtype<<<1, 64, 0, stream>>>((const unsigned short*)x, flag);

    normalize_kernel<<<(B_ROWS * DIN + 255) / 256, 256, 0, stream>>>(x, xn, flag, B_ROWS * DIN);
    normalize_kernel<<<(B_ROWS * 8 + 255) / 256, 256, 0, stream>>>(gum, gumn, flag, B_ROWS * 8);
    normalize_kernel<<<(DIN * 8 + 255) / 256, 256, 0, stream>>>(gw, gwn, flag, DIN * 8);
    normalize_kernel<<<1, 256, 0, stream>>>(gb, gbn, flag, 8);
    normalize_kernel<<<(NE * DH + 255) / 256, 256, 0, stream>>>(b1, b1n, flag, NE * DH);
    normalize_kernel<<<(NE * DOUT + 255) / 256, 256, 0, stream>>>(b2, b2n, flag, NE * DOUT);

    gating_kernel<<<256, 256, 0, stream>>>(xn, gumn, gwn, gbn, probs, partials);
    aux_finalize<<<1, 64, 0, stream>>>(partials, d_out, flag);

    transpose_cvt<<<dim3(DH / 64, DIN / 64, NE), dim3(64, 4), 0, stream>>>(
        w1, w1Tcat, DIN, DH, DIN, (size_t)DH * DIN, flag);
    transpose_cvt<<<dim3(DOUT / 64, DH / 64, NE), dim3(64, 4), 0, stream>>>(
        w2, w2Tcat, DH, DOUT, NCAT, (size_t)DH, flag);

    for (int c0 = 0; c0 < B_ROWS; c0 += R) {
        gemm256<DIN, 0><<<dim3(R / 256, NCAT / 256, 1), 512, 0, stream>>>(
            xn + (size_t)c0 * DIN, w1Tcat, b1n, probs + (size_t)c0 * 8, Hcat,
            nullptr, R, DIN, 1);
        gemm256<NCAT, 1><<<dim3(R / 256, DOUT / 256, KS), 512, 0, stream>>>(
            Hcat, w2Tcat, nullptr, nullptr, nullptr,
            partial, R, klen, 0);
        out_finalize<<<(R * DOUT) / 256, 256, 0, stream>>>(
            partial, b2n, probs + (size_t)c0 * 8, d_out, (size_t)c0 * DOUT, flag, R, KS);
    }
}